// Round 7
// baseline (255.911 us; speedup 1.0000x reference)
//
#include <hip/hip_runtime.h>
#include <math.h>

#define GN 2048
#define GD_IN 128
#define GD_OUT 64

typedef float f4 __attribute__((ext_vector_type(4)));

// Kernel 1: h = X @ W^T  [N, D_OUT]; s_i = h @ a[:64]; s_j = h @ a[64:]
__global__ __launch_bounds__(64) void gat_h_kernel(
    const float* __restrict__ x,   // [N, 128]
    const float* __restrict__ W,   // [64, 128]
    const float* __restrict__ a,   // [128]
    float* __restrict__ h,         // [N, 64]
    float* __restrict__ s_i,       // [N]
    float* __restrict__ s_j) {     // [N]
    __shared__ float wl[GD_OUT * (GD_IN + 1)];
    __shared__ float xl[GD_IN];
    const int i = blockIdx.x;
    const int t = threadIdx.x;  // 0..63

    for (int idx = t; idx < GD_OUT * GD_IN; idx += 64) {
        int o = idx >> 7, k = idx & 127;
        wl[o * (GD_IN + 1) + k] = W[idx];
    }
    xl[t]      = x[i * GD_IN + t];
    xl[t + 64] = x[i * GD_IN + t + 64];
    __syncthreads();

    float acc = 0.f;
    const float* wr = &wl[t * (GD_IN + 1)];
    #pragma unroll
    for (int k = 0; k < GD_IN; ++k) acc = fmaf(xl[k], wr[k], acc);
    h[i * GD_OUT + t] = acc;

    float p1 = acc * a[t];
    float p2 = acc * a[GD_OUT + t];
    #pragma unroll
    for (int off = 32; off; off >>= 1) {
        p1 += __shfl_down(p1, off);
        p2 += __shfl_down(p2, off);
    }
    if (t == 0) { s_i[i] = p1; s_j[i] = p2; }
}

// Kernel 2: R3's softmax prologue, but emits PRESCALED alpha to global ws.
__global__ __launch_bounds__(256) void gat_alpha_kernel(
    const int* __restrict__ mask,  // [N, N]
    const float* __restrict__ s_i, // [N]
    const float* __restrict__ s_j, // [N]
    float* __restrict__ alphag) {  // [N, N]
    __shared__ float sc[GN];
    __shared__ float red[4];
    const int i = blockIdx.x;
    const int t = threadIdx.x;  // 0..255
    const float si = s_i[i];

    float lmax = -INFINITY;
    for (int j = t; j < GN; j += 256) {
        float z = si + s_j[j];
        float s = z > 0.f ? z : 0.01f * z;
        s = mask[(size_t)i * GN + j] ? s : -INFINITY;
        sc[j] = s;
        lmax = fmaxf(lmax, s);
    }
    #pragma unroll
    for (int off = 32; off; off >>= 1) lmax = fmaxf(lmax, __shfl_down(lmax, off));
    if ((t & 63) == 0) red[t >> 6] = lmax;
    __syncthreads();
    float rmax = fmaxf(fmaxf(red[0], red[1]), fmaxf(red[2], red[3]));
    if (rmax == -INFINITY) rmax = 0.f;  // all-invalid row -> alpha row = 0

    float lsum = 0.f;
    for (int j = t; j < GN; j += 256) {
        float e = __expf(sc[j] - rmax);
        sc[j] = e;
        lsum += e;
    }
    #pragma unroll
    for (int off = 32; off; off >>= 1) lsum += __shfl_down(lsum, off);
    __syncthreads();
    if ((t & 63) == 0) red[t >> 6] = lsum;
    __syncthreads();
    const float ssum = red[0] + red[1] + red[2] + red[3];
    const float inv = ssum > 0.f ? 1.f / ssum : 0.f;

    for (int j = t; j < GN; j += 256)
        alphag[(size_t)i * GN + j] = sc[j] * inv;
}

// Kernel 3: minimal dependent writer (fill-clone + 1 dword load + v_mul).
// Thread owns fixed (io, j, o4): hv in register; per iter 1 alpha dword
// (16-lane broadcast) + 1 dwordx4 store. Dense 2MB chip-wide front.
__global__ __launch_bounds__(256) void gat_write_kernel(
    const float* __restrict__ alphag,  // [N, N] prescaled
    const float* __restrict__ h,       // [N, 64]
    f4* __restrict__ out4) {           // [N*N*16]
    const int gid = blockIdx.x * 256 + threadIdx.x;  // 0..131071
    const int o4 = gid & 15;
    const int j  = (gid >> 4) & (GN - 1);
    const int io = gid >> 15;                         // 0..3
    const f4 hv = reinterpret_cast<const f4*>(h)[(j << 4) | o4];

    const float* __restrict__ ap = alphag + (size_t)io * GN + j;
    f4* __restrict__ op = out4 + ((((size_t)io * GN + j) << 4) | o4);
    #pragma unroll 4
    for (int it = 0; it < GN / 4; ++it) {
        float al = ap[(size_t)it * 4 * GN];           // one dword / 16 lanes
        op[(size_t)it * 4 * GN * 16] = hv * al;       // 1KB/wave dense store
    }
}

extern "C" void kernel_launch(void* const* d_in, const int* in_sizes, int n_in,
                              void* d_out, int out_size, void* d_ws, size_t ws_size,
                              hipStream_t stream) {
    const float* x    = (const float*)d_in[0];   // [2048, 128]
    const int*   mask = (const int*)d_in[1];     // [2048, 2048]
    const float* W    = (const float*)d_in[2];   // [64, 128]
    const float* a    = (const float*)d_in[3];   // [128]
    float* out = (float*)d_out;                  // [2048, 2048, 64]

    float* ws   = (float*)d_ws;
    float* h    = ws;                  // 131072 floats
    float* s_i  = ws + GN * GD_OUT;    // 2048
    float* s_j  = s_i + GN;            // 2048
    float* alphag = s_j + GN;          // 2048*2048 floats = 16.8 MB

    gat_h_kernel<<<GN, 64, 0, stream>>>(x, W, a, h, s_i, s_j);
    gat_alpha_kernel<<<GN, 256, 0, stream>>>(mask, s_i, s_j, alphag);
    gat_write_kernel<<<512, 256, 0, stream>>>(alphag, h, (f4*)out);
}

// Round 8
// 214.693 us; speedup vs baseline: 1.1920x; 1.1920x over previous
//
#include <hip/hip_runtime.h>
#include <math.h>

#define GN 2048
#define GD_IN 128
#define GD_OUT 64

typedef float f4 __attribute__((ext_vector_type(4)));

// Kernel 1: h = X @ W^T  [N, D_OUT]; s_i = h @ a[:64]; s_j = h @ a[64:]
__global__ __launch_bounds__(64) void gat_h_kernel(
    const float* __restrict__ x,   // [N, 128]
    const float* __restrict__ W,   // [64, 128]
    const float* __restrict__ a,   // [128]
    float* __restrict__ h,         // [N, 64]
    float* __restrict__ s_i,       // [N]
    float* __restrict__ s_j) {     // [N]
    __shared__ float wl[GD_OUT * (GD_IN + 1)];  // +1 pad -> conflict-free
    __shared__ float xl[GD_IN];
    const int i = blockIdx.x;
    const int t = threadIdx.x;  // 0..63

    for (int idx = t; idx < GD_OUT * GD_IN; idx += 64) {
        int o = idx >> 7, k = idx & 127;
        wl[o * (GD_IN + 1) + k] = W[idx];
    }
    xl[t]      = x[i * GD_IN + t];
    xl[t + 64] = x[i * GD_IN + t + 64];
    __syncthreads();

    float acc = 0.f;
    const float* wr = &wl[t * (GD_IN + 1)];
    #pragma unroll
    for (int k = 0; k < GD_IN; ++k) acc = fmaf(xl[k], wr[k], acc);
    h[i * GD_OUT + t] = acc;

    float p1 = acc * a[t];
    float p2 = acc * a[GD_OUT + t];
    #pragma unroll
    for (int off = 32; off; off >>= 1) {
        p1 += __shfl_down(p1, off);
        p2 += __shfl_down(p2, off);
    }
    if (t == 0) { s_i[i] = p1; s_j[i] = p2; }
}

// Kernel 2 (fused): one block per row i. Masked leaky-relu scores -> softmax
// -> prescaled alpha in LDS -> stream messages[i,j,:] = alpha[i,j] * h[j,:].
// NOTE (measured, rounds 1-7): fused beats decoupled by 35-40us (prologue
// hides under other resident blocks' write phases); plain stores beat NT;
// rotation/reuse/minimal-writer variants all null or negative. Best: 214.6us.
__global__ __launch_bounds__(256) void gat_msg_kernel(
    const int* __restrict__ mask,  // [N, N] int32 (0/1)
    const float* __restrict__ h,   // [N, 64]
    const float* __restrict__ s_i, // [N]
    const float* __restrict__ s_j, // [N]
    float* __restrict__ out) {     // [N, N, 64]
    __shared__ float sc[GN];   // scores -> exp -> alpha
    __shared__ float red[4];
    const int i = blockIdx.x;
    const int t = threadIdx.x;  // 0..255
    const float si = s_i[i];

    // Pass 1: masked leaky-relu scores + local max
    float lmax = -INFINITY;
    for (int j = t; j < GN; j += 256) {
        float z = si + s_j[j];
        float s = z > 0.f ? z : 0.01f * z;
        s = mask[(size_t)i * GN + j] ? s : -INFINITY;
        sc[j] = s;
        lmax = fmaxf(lmax, s);
    }
    #pragma unroll
    for (int off = 32; off; off >>= 1) lmax = fmaxf(lmax, __shfl_down(lmax, off));
    if ((t & 63) == 0) red[t >> 6] = lmax;
    __syncthreads();
    float rmax = fmaxf(fmaxf(red[0], red[1]), fmaxf(red[2], red[3]));
    if (rmax == -INFINITY) rmax = 0.f;  // all-invalid row -> alpha row = 0

    // Pass 2: exp + local sum
    float lsum = 0.f;
    for (int j = t; j < GN; j += 256) {
        float e = __expf(sc[j] - rmax);   // exp(-inf) == 0 for unmasked
        sc[j] = e;
        lsum += e;
    }
    #pragma unroll
    for (int off = 32; off; off >>= 1) lsum += __shfl_down(lsum, off);
    __syncthreads();
    if ((t & 63) == 0) red[t >> 6] = lsum;
    __syncthreads();
    const float ssum = red[0] + red[1] + red[2] + red[3];
    const float inv = ssum > 0.f ? 1.f / ssum : 0.f;

    // Pass 3: prescale alpha in place (each thread owns its sc slots)
    for (int j = t; j < GN; j += 256) sc[j] *= inv;
    __syncthreads();

    // Write phase: 16 j's x 16 float4-lanes per iteration, PLAIN stores.
    const f4* __restrict__ h4 = reinterpret_cast<const f4*>(h);
    f4* __restrict__ out4 = reinterpret_cast<f4*>(out) + (size_t)i * GN * (GD_OUT / 4);
    const int jl = t >> 4;   // 0..15
    const int o4 = t & 15;   // 0..15
    #pragma unroll 4
    for (int jb = 0; jb < GN; jb += 16) {
        int j = jb + jl;
        float al = sc[j];                // LDS broadcast (16 lanes share j)
        f4 hv = h4[j * (GD_OUT / 4) + o4];
        out4[(size_t)j * (GD_OUT / 4) + o4] = hv * al;
    }
}

extern "C" void kernel_launch(void* const* d_in, const int* in_sizes, int n_in,
                              void* d_out, int out_size, void* d_ws, size_t ws_size,
                              hipStream_t stream) {
    const float* x    = (const float*)d_in[0];   // [2048, 128]
    const int*   mask = (const int*)d_in[1];     // [2048, 2048]
    const float* W    = (const float*)d_in[2];   // [64, 128]
    const float* a    = (const float*)d_in[3];   // [128]
    float* out = (float*)d_out;                  // [2048, 2048, 64]

    float* ws  = (float*)d_ws;
    float* h   = ws;                 // 2048*64 floats
    float* s_i = ws + GN * GD_OUT;   // 2048 floats
    float* s_j = s_i + GN;           // 2048 floats

    gat_h_kernel<<<GN, 64, 0, stream>>>(x, W, a, h, s_i, s_j);
    gat_msg_kernel<<<GN, 256, 0, stream>>>(mask, h, s_i, s_j, out);
}